// Round 10
// baseline (355.394 us; speedup 1.0000x reference)
//
#include <hip/hip_runtime.h>
#include <stdint.h>

#define B 4
#define N 16384
#define D 512
#define H 256
#define NROWS (B * N)
#define K_SEL 11468
#define N_TOP 10322
#define N_RAND 1146
#define N_REM (N - N_TOP) /* 6062 */
#define HALF_CNT ((B * N_REM) / 2) /* 12124 */

typedef float f32x4 __attribute__((ext_vector_type(4)));
typedef _Float16 f16x8 __attribute__((ext_vector_type(8)));
typedef int i32x4 __attribute__((ext_vector_type(4)));

// async global->LDS 16B copy: LDS dest = wave-uniform base + lane*16
#define GLDS16(g, l)                                                    \
  __builtin_amdgcn_global_load_lds(                                     \
      (const __attribute__((address_space(1))) void*)(const void*)(g),  \
      (__attribute__((address_space(3))) void*)(void*)(l), 16, 0, 0)

#define SCHED0 __builtin_amdgcn_sched_barrier(0)
#define SBAR __builtin_amdgcn_s_barrier

// Monotone float -> uint key (larger float => larger key). No NaNs expected.
__device__ __forceinline__ uint32_t f2key(float x) {
  uint32_t u = __float_as_uint(x);
  return u ^ ((u & 0x80000000u) ? 0xFFFFFFFFu : 0x80000000u);
}

// ---- Threefry (matches jax.random.uniform(key(42)) stream) ---------------
__device__ __forceinline__ void threefry(uint32_t x0, uint32_t x1,
                                         uint32_t& o0, uint32_t& o1) {
  const uint32_t k0 = 0u, k1 = 42u;
  const uint32_t ks[3] = {k0, k1, k0 ^ k1 ^ 0x1BD11BDAu};
  x0 += ks[0];
  x1 += ks[1];
  const int R0[4] = {13, 15, 26, 6}, R1[4] = {17, 29, 16, 24};
#pragma unroll
  for (int i = 0; i < 5; ++i) {
    const int* R = (i & 1) ? R1 : R0;
#pragma unroll
    for (int jr = 0; jr < 4; ++jr) {
      x0 += x1;
      x1 = (x1 << R[jr]) | (x1 >> (32 - R[jr]));
      x1 ^= x0;
    }
    x0 += ks[(i + 1) % 3];
    x1 += ks[(i + 2) % 3] + (uint32_t)(i + 1);
  }
  o0 = x0;
  o1 = x1;
}

// ---- rand body: pick N_RAND smallest threefry scores -> psel bitmap ------
__device__ __forceinline__ void rand_body(const int b, int* __restrict__ psel,
                                          char* smem, const int t) {
  uint32_t* skey = reinterpret_cast<uint32_t*>(smem);           // N_REM*4
  uint32_t* hist = reinterpret_cast<uint32_t*>(smem + 24248);   // 256*4
  int* wr4 = reinterpret_cast<int*>(smem + 25272);              // 4*4
  uint32_t* shp = reinterpret_cast<uint32_t*>(smem + 25288);
  int* shrk = reinterpret_cast<int*>(smem + 25292);
  const int lane = t & 63, w4 = t >> 6;  // 4 waves

  for (int p = t; p < N_REM; p += 256) {
    psel[b * N_REM + p] = 0;
    const int f = b * N_REM + p;
    uint32_t o0, o1, bits;
    if (f < HALF_CNT) {
      threefry((uint32_t)f, (uint32_t)(f + HALF_CNT), o0, o1);
      bits = o0;
    } else {
      threefry((uint32_t)(f - HALF_CNT), (uint32_t)f, o0, o1);
      bits = o1;
    }
    const float u = __uint_as_float((bits >> 9) | 0x3f800000u) - 1.0f;
    skey[p] = f2key(u);
  }
  __syncthreads();

  uint32_t prefix = 0;
  int rk = N_RAND;
  for (int pass = 3; pass >= 0; --pass) {
    const int sh = pass * 8;
    hist[t] = 0;
    __syncthreads();
    for (int p = t; p < N_REM; p += 256) {
      const uint32_t key = skey[p];
      if (pass == 3 || (key >> (sh + 8)) == (prefix >> (sh + 8)))
        atomicAdd(&hist[(key >> sh) & 255], 1u);
    }
    __syncthreads();
    const int h = (int)hist[t];
    int v = h;
#pragma unroll
    for (int off = 1; off < 64; off <<= 1) {
      const int u2 = __shfl_up(v, off, 64);
      if (lane >= off) v += u2;
    }
    if (lane == 63) wr4[w4] = v;
    __syncthreads();
    int add = 0;
    for (int i = 0; i < w4; ++i) add += wr4[i];
    const int incl = v + add, excl = incl - h;
    if (incl >= rk && excl < rk) {
      *shp = prefix | ((uint32_t)t << sh);
      *shrk = rk - excl;
    }
    __syncthreads();
    prefix = *shp;
    rk = *shrk;
    __syncthreads();
  }

  const int CH = 24;  // 256*24 >= 6062
  const int p0 = t * CH;
  const int pe = (p0 + CH < N_REM) ? p0 + CH : N_REM;
  int ce = 0;
  for (int p = p0; p < pe; ++p) ce += (skey[p] == prefix);
  int v = ce;
#pragma unroll
  for (int off = 1; off < 64; off <<= 1) {
    const int u2 = __shfl_up(v, off, 64);
    if (lane >= off) v += u2;
  }
  if (lane == 63) wr4[w4] = v;
  __syncthreads();
  if (t == 0) {
    int run = 0;
    for (int i = 0; i < 4; ++i) {
      const int a = wr4[i];
      wr4[i] = run;
      run += a;
    }
  }
  __syncthreads();
  int ge = wr4[w4] + v - ce;
  for (int p = p0; p < pe; ++p) {
    const uint32_t key = skey[p];
    const bool pick = (key < prefix) || (key == prefix && ge < rk);
    ge += (key == prefix);
    if (pick) psel[b * N_REM + p] = 1;
  }
}

// ---- K0: fused prep.
// Blocks 0-63: W^T fp16 hi/lo, step/col-half-chunked + granule-permuted
//   (layout identical to R6; writer remapped so each thread writes 2x16B
//   CONTIGUOUS granules -> fully coalesced stores, was 64B-stride scatter).
// Blocks 64-67: rand selection. Blocks 68-131: zero ghist16 (1 MB).
__global__ __launch_bounds__(256) void prep_kernel(
    const float* __restrict__ WV, const float* __restrict__ WU,
    _Float16* __restrict__ wt_h, _Float16* __restrict__ wt_l,
    int* __restrict__ psel, uint32_t* __restrict__ ghist16) {
  __shared__ __align__(16) char pmem[25296];
  if (blockIdx.x >= 68) {
    uint32_t* g = ghist16 + (size_t)(blockIdx.x - 68) * 4096;
    for (int i = threadIdx.x; i < 4096; i += 256) g[i] = 0;
    return;
  }
  if (blockIdx.x >= 64) {
    rand_body(blockIdx.x - 64, psel, pmem, threadIdx.x);
    return;
  }
  _Float16(*th)[65] = reinterpret_cast<_Float16(*)[65]>(pmem);
  _Float16(*tl)[65] = reinterpret_cast<_Float16(*)[65]>(pmem + 8320);
  const int kb = (blockIdx.x >> 3) * 64;
  const int nb = (blockIdx.x & 7) * 64;
  const int tx = threadIdx.x & 63;
  const int ty = threadIdx.x >> 6;
  const float* src = (nb < 256) ? WV : WU;
  const int nsrc = nb & 255;
#pragma unroll
  for (int i = 0; i < 16; ++i) {
    const int k = ty + i * 4;
    const float x = src[(size_t)(kb + k) * H + nsrc + tx];
    const _Float16 h = (_Float16)x;
    th[k][tx] = h;
    tl[k][tx] = (_Float16)(x - (float)h);
  }
  __syncthreads();
  // coalesced writer: region r = s_local (tid>>7), thread q = tid&127
  // writes granules gi = 2q, 2q+1 of the contiguous 4KB region
  // (row nll = gi>>2, slot = gi&3; source granule gsrc = slot ^ swz(nll)).
  const int r = threadIdx.x >> 7;
  const int q = threadIdx.x & 127;
  const int ch2 = (nb & 255) >> 7;
  const int nlbase = ((nb < 256) ? 0 : 128) + (nb & 127);
  const size_t base =
      (size_t)((kb >> 5) + r) * 16384 + (size_t)ch2 * 8192 + (size_t)nlbase * 32;
#pragma unroll
  for (int u = 0; u < 2; ++u) {
    const int gi = q * 2 + u;
    const int slot = gi & 3;
    const int nll = gi >> 2;  // local row 0..63
    const int swz = (nll >> 1) & 3;  // nlbase is 0 mod 64
    const int gsrc = slot ^ swz;
    const int kb8 = r * 32 + gsrc * 8;
    f16x8 vh, vl;
#pragma unroll
    for (int e = 0; e < 8; ++e) {
      vh[e] = th[kb8 + e][nll];
      vl[e] = tl[kb8 + e][nll];
    }
    *reinterpret_cast<f16x8*>(wt_h + base + (size_t)gi * 8) = vh;
    *reinterpret_cast<f16x8*>(wt_l + base + (size_t)gi * 8) = vl;
  }
}

// ---- K1: fused gated-attention raw scores via MFMA (fp16 hi/lo split).
// R9 structure kept verbatim (2 blocks/CU, conflict-free swizzle, raw
// barriers) — measured at its structural ceiling ~108 us.
__global__ __launch_bounds__(512, 4) void score_kernel(
    const float* __restrict__ feat, const _Float16* __restrict__ wt_h,
    const _Float16* __restrict__ wt_l, const float* __restrict__ bV,
    const float* __restrict__ bU, const float* __restrict__ watt,
    float* __restrict__ rawp) {
  __shared__ _Float16 Ah[128 * 32];   // 8 KB
  __shared__ _Float16 Al[128 * 32];   // 8 KB
  __shared__ _Float16 Bh0[256 * 32];  // 16 KB
  __shared__ _Float16 Bl0[256 * 32];  // 16 KB
  __shared__ _Float16 Bh1[256 * 32];  // 16 KB
  __shared__ _Float16 Bl1[256 * 32];  // 16 KB
  float* red = reinterpret_cast<float*>(Ah);  // [128][5] epilogue alias

  const int tid = threadIdx.x;
  const int lane = tid & 63;
  const int lc = lane & 15;
  const int lg = lane >> 4;
  const int w = __builtin_amdgcn_readfirstlane(tid >> 6);
  const int rg = w >> 2;  // 0..1
  const int cg = w & 3;   // 0..3
  const int bid = blockIdx.x;
  const int c = bid & 1;
  const int row0 = (bid >> 1) * 128;
  const int phase = (bid & 3) * 4;  // k-phase stagger

  const int rA = tid >> 2;
  const int gA = tid & 3;
  const float* aG = feat + (size_t)(row0 + rA) * D + gA * 8;
  const int awOff = rA * 32 + ((gA ^ ((rA >> 1) & 3)) << 3);

  const _Float16* pbh = wt_h + (size_t)c * 8192 + (size_t)w * 1024 + lane * 8;
  const _Float16* pbl = wt_l + (size_t)c * 8192 + (size_t)w * 1024 + lane * 8;
  const int ldsB = w * 1024;  // f16 idx

  const int rswz = (lc >> 1) & 3;
  int aoff[4], boff[4];
#pragma unroll
  for (int mt = 0; mt < 4; ++mt)
    aoff[mt] = (rg * 64 + mt * 16 + lc) * 32 + ((lg ^ rswz) << 3);
#pragma unroll
  for (int nt = 0; nt < 4; ++nt) {
    const int nl =
        ((nt < 2) ? cg * 32 + nt * 16 : 128 + cg * 32 + (nt - 2) * 16) + lc;
    boff[nt] = nl * 32 + ((lg ^ rswz) << 3);
  }

  f32x4 acc[4][4] = {};
  f32x4 a0, a1;

  a0 = *(const f32x4*)(aG + phase * 32);
  a1 = *(const f32x4*)(aG + phase * 32 + 4);
  GLDS16(pbh + phase * 16384, &Bh0[ldsB]);
  GLDS16(pbh + phase * 16384 + 512, &Bh0[ldsB + 512]);
  GLDS16(pbl + phase * 16384, &Bl0[ldsB]);
  GLDS16(pbl + phase * 16384 + 512, &Bl0[ldsB + 512]);
  {
    f16x8 ahw, alw;
#pragma unroll
    for (int e = 0; e < 8; ++e) {
      const float x = (e < 4) ? a0[e] : a1[e - 4];
      const _Float16 h = (_Float16)x;
      ahw[e] = h;
      alw[e] = (_Float16)(x - (float)h);
    }
    *(f16x8*)&Ah[awOff] = ahw;
    *(f16x8*)&Al[awOff] = alw;
  }
  SCHED0;
  asm volatile("s_waitcnt lgkmcnt(0)" ::: "memory");
  asm volatile("s_waitcnt vmcnt(0)" ::: "memory");
  SBAR();
  SCHED0;

#pragma unroll 1
  for (int i = 0; i < 16; ++i) {
    const int knxs = (phase + i + 1) & 15;
    _Float16* BhN = (i & 1) ? Bh0 : Bh1;
    _Float16* BlN = (i & 1) ? Bl0 : Bl1;
    const _Float16* BhC = (i & 1) ? Bh1 : Bh0;
    const _Float16* BlC = (i & 1) ? Bl1 : Bl0;

    GLDS16(pbh + knxs * 16384, &BhN[ldsB]);
    GLDS16(pbh + knxs * 16384 + 512, &BhN[ldsB + 512]);
    GLDS16(pbl + knxs * 16384, &BlN[ldsB]);
    GLDS16(pbl + knxs * 16384 + 512, &BlN[ldsB + 512]);
    a0 = *(const f32x4*)(aG + knxs * 32);
    a1 = *(const f32x4*)(aG + knxs * 32 + 4);
    SCHED0;

    f16x8 ah[4], al[4];
#pragma unroll
    for (int mt = 0; mt < 4; ++mt) {
      ah[mt] = *(const f16x8*)&Ah[aoff[mt]];
      al[mt] = *(const f16x8*)&Al[aoff[mt]];
    }
    __builtin_amdgcn_s_setprio(1);
#pragma unroll
    for (int nt = 0; nt < 4; ++nt) {
      const f16x8 bh = *(const f16x8*)&BhC[boff[nt]];
      const f16x8 bl = *(const f16x8*)&BlC[boff[nt]];
#pragma unroll
      for (int mt = 0; mt < 4; ++mt)
        acc[mt][nt] = __builtin_amdgcn_mfma_f32_16x16x32_f16(ah[mt], bh,
                                                             acc[mt][nt], 0, 0, 0);
#pragma unroll
      for (int mt = 0; mt < 4; ++mt)
        acc[mt][nt] = __builtin_amdgcn_mfma_f32_16x16x32_f16(ah[mt], bl,
                                                             acc[mt][nt], 0, 0, 0);
#pragma unroll
      for (int mt = 0; mt < 4; ++mt)
        acc[mt][nt] = __builtin_amdgcn_mfma_f32_16x16x32_f16(al[mt], bh,
                                                             acc[mt][nt], 0, 0, 0);
    }
    __builtin_amdgcn_s_setprio(0);

    f16x8 ahw, alw;
#pragma unroll
    for (int e = 0; e < 8; ++e) {
      const float x = (e < 4) ? a0[e] : a1[e - 4];
      const _Float16 h = (_Float16)x;
      ahw[e] = h;
      alw[e] = (_Float16)(x - (float)h);
    }
    SCHED0;
    SBAR();
    SCHED0;
    *(f16x8*)&Ah[awOff] = ahw;
    *(f16x8*)&Al[awOff] = alw;
    SCHED0;
    asm volatile("s_waitcnt lgkmcnt(0)" ::: "memory");
    asm volatile("s_waitcnt vmcnt(0)" ::: "memory");
    SBAR();
    SCHED0;
  }

#pragma unroll
  for (int mt = 0; mt < 4; ++mt) {
    float rs[4] = {0.f, 0.f, 0.f, 0.f};
#pragma unroll
    for (int nt = 0; nt < 2; ++nt) {
      const int j = c * 128 + cg * 32 + nt * 16 + lc;
      const float bv = bV[j], bu = bU[j], wa = watt[j];
#pragma unroll
      for (int rr = 0; rr < 4; ++rr) {
        const float cV = acc[mt][nt][rr] + bv;
        const float cU = acc[mt][nt + 2][rr] + bu;
        const float e2 = __expf(2.0f * cV);
        const float aV = 1.0f - 2.0f / (e2 + 1.0f);    // tanh
        const float aU = 1.0f / (1.0f + __expf(-cU));  // sigmoid
        rs[rr] += aV * aU * wa;
      }
    }
#pragma unroll
    for (int rr = 0; rr < 4; ++rr) {
      float v = rs[rr];
      v += __shfl_xor(v, 1, 16);
      v += __shfl_xor(v, 2, 16);
      v += __shfl_xor(v, 4, 16);
      v += __shfl_xor(v, 8, 16);
      if (lc == 0) red[(rg * 64 + mt * 16 + lg * 4 + rr) * 5 + cg] = v;
    }
  }
  __syncthreads();
  if (tid < 128)
    rawp[(size_t)c * NROWS + row0 + tid] = red[tid * 5 + 0] + red[tid * 5 + 1] +
                                           red[tid * 5 + 2] + red[tid * 5 + 3];
}

// ---- K2b: sum partials in-place, exp-sum partials, top-16-bit histogram.
// 128 blocks x 512 thr (1 elem/thread). No max-shift needed: |raw| <= ~13
// (|tanh*sig|<=1 summed against watt) -> exp <= 4e5, no overflow; attn
// perturbation ~1e-7 relative. Integer hist atomics are deterministic;
// exp-sums use per-block partials (fixed order) -> deterministic.
__global__ __launch_bounds__(512) void sumhist_kernel(
    float* rawp, uint32_t* __restrict__ ghist16, float* __restrict__ gpart) {
  const int bid = blockIdx.x;
  const int b = bid >> 5;
  const int blk = bid & 31;
  const int idx = b * N + blk * 512 + threadIdx.x;
  const float v = rawp[idx] + rawp[(size_t)NROWS + idx];
  rawp[idx] = v;  // in-place: select reads summed raw from region 0
  atomicAdd(&ghist16[((size_t)b << 16) + (f2key(v) >> 16)], 1u);
  float e = __expf(v);
  for (int off = 32; off > 0; off >>= 1) e += __shfl_down(e, off, 64);
  __shared__ float wsum[8];
  const int lane = threadIdx.x & 63, wv = threadIdx.x >> 6;
  if (lane == 0) wsum[wv] = e;
  __syncthreads();
  if (threadIdx.x == 0) {
    float s = 0.f;
    for (int i = 0; i < 8; ++i) s += wsum[i];
    gpart[b * 32 + blk] = s;
  }
}

// ---- exclusive scan over 1024 per-thread counts --------------------------
__device__ __forceinline__ int scan1024(int c, int* wred, int tid) {
  const int lane = tid & 63, w = tid >> 6;
  int v = c;
#pragma unroll
  for (int off = 1; off < 64; off <<= 1) {
    const int u = __shfl_up(v, off, 64);
    if (lane >= off) v += u;
  }
  if (lane == 63) wred[w] = v;
  __syncthreads();
  if (tid == 0) {
    int run = 0;
    for (int i = 0; i < 16; ++i) {
      const int a = wred[i];
      wred[i] = run;
      run += a;
    }
  }
  __syncthreads();
  const int res = wred[w] + v - c;
  __syncthreads();
  return res;
}

// ---- K3: attn + top-k threshold (hist16 + 2-pass refine) + compaction ----
__global__ __launch_bounds__(1024) void select_kernel(
    const float* __restrict__ rawp, const int* __restrict__ psel,
    const uint32_t* __restrict__ ghist16, const float* __restrict__ gpart,
    float* __restrict__ attn_out, int* __restrict__ sel_ws,
    float* __restrict__ out_selidx) {
  const int b = blockIdx.x, t = threadIdx.x;
  const int lane = t & 63, w = t >> 6;
  __shared__ float sraw[N];        // 64 KB
  __shared__ int whist[16][256];   // 16 KB
  __shared__ int ghist[256];
  __shared__ int wred[16];
  __shared__ float shS;
  __shared__ uint32_t sh_prefix;
  __shared__ int sh_rk;
  const float* r0 = rawp + (size_t)b * N;  // summed raw (from sumhist)

  // 0. exp-sum from partials
  if (t < 64) {
    float s = (t < 32) ? gpart[b * 32 + t] : 0.0f;
    for (int off = 32; off > 0; off >>= 1) s += __shfl_down(s, off, 64);
    if (t == 0) shS = s;
  }
  __syncthreads();
  const float inv = 1.0f / shS;

  // 1. load raw + attn write (no max-shift; see sumhist comment)
  for (int i = 0; i < 16; ++i) {
    const int idx = t + i * 1024;
    const float v = r0[idx];
    sraw[idx] = v;
    attn_out[b * N + idx] = __expf(v) * inv;
  }

  // 2. threshold top-16 bits from global histogram.
  // thread t owns bins [64t, 64t+63]; find P s.t.
  // cnt(top16 > P) < N_TOP <= cnt(top16 >= P); rk = N_TOP - cnt(top16 > P).
  const uint32_t* hb = ghist16 + ((size_t)b << 16);
  int qs[16];
  int loc = 0;
#pragma unroll
  for (int qq = 0; qq < 16; ++qq) {
    const i32x4 h4 = *reinterpret_cast<const i32x4*>(hb + (t << 6) + (qq << 2));
    qs[qq] = h4[0] + h4[1] + h4[2] + h4[3];
    loc += qs[qq];
  }
  const int excl2 = scan1024(loc, wred, t);
  const int incl2 = excl2 + loc;
  const int above_end = N - incl2;  // keys in bins above t's range
  if (above_end < N_TOP && (N - excl2) >= N_TOP) {
    int run = above_end;
    int fq = -1, rrun = 0;
#pragma unroll
    for (int qq = 15; qq >= 0; --qq) {
      if (fq < 0) {
        if (run + qs[qq] >= N_TOP) { fq = qq; rrun = run; }
        else run += qs[qq];
      }
    }
    const i32x4 h4 = *reinterpret_cast<const i32x4*>(hb + (t << 6) + (fq << 2));
    int run2 = rrun;
    int fj = -1;
#pragma unroll
    for (int jj = 3; jj >= 0; --jj) {
      if (fj < 0) {
        const int cb = h4[jj];
        if (run2 + cb >= N_TOP) {
          fj = jj;
          sh_prefix = ((uint32_t)((t << 6) + (fq << 2) + jj)) << 16;
          sh_rk = N_TOP - run2;
        } else {
          run2 += cb;
        }
      }
    }
  }
  __syncthreads();
  uint32_t prefix = sh_prefix;
  int rk = sh_rk;
  __syncthreads();

  // 3. refine low 16 bits: 2 radix passes (same machinery as before; the
  // pass predicate compares bits above sh+8 to prefix, which now carries P).
  for (int pass = 1; pass >= 0; --pass) {
    const int sh = pass * 8;
#pragma unroll
    for (int qz = 0; qz < 4; ++qz) whist[w][lane * 4 + qz] = 0;
    __syncthreads();
    for (int i = 0; i < 16; ++i) {
      const uint32_t key = f2key(sraw[t + i * 1024]);
      if ((key >> (sh + 8)) == (prefix >> (sh + 8)))
        atomicAdd(&whist[w][(key >> sh) & 255], 1);
    }
    __syncthreads();
    if (t < 256) {
      int tot = 0;
      for (int ww = 0; ww < 16; ++ww) tot += whist[ww][t];
      ghist[t] = tot;
    }
    __syncthreads();
    int vS = 0, hrev = 0;
    if (t < 256) {
      hrev = ghist[255 - t];
      vS = hrev;
#pragma unroll
      for (int off = 1; off < 64; off <<= 1) {
        const int u2 = __shfl_up(vS, off, 64);
        if (lane >= off) vS += u2;
      }
      if (lane == 63) wred[t >> 6] = vS;
    }
    __syncthreads();
    if (t < 256) {
      int add = 0;
      const int w4 = t >> 6;
      for (int i = 0; i < w4; ++i) add += wred[i];
      const int incl = vS + add, excl = incl - hrev;
      if (incl >= rk && excl < rk) {
        sh_prefix = prefix | ((uint32_t)(255 - t) << sh);
        sh_rk = rk - excl;
      }
    }
    __syncthreads();
    prefix = sh_prefix;
    rk = sh_rk;
    __syncthreads();
  }
  const uint32_t T = prefix;
  const int tieTake = rk;

  // 4. membership + p-rank + psel lookup + selection (contiguous chunks)
  const int n0 = t * 16;
  int cgt = 0, ceq = 0;
  for (int i = 0; i < 16; ++i) {
    const uint32_t key = f2key(sraw[n0 + i]);
    cgt += (key > T);
    ceq += (key == T);
  }
  const int gbase = scan1024(cgt, wred, t);
  const int ebase = scan1024(ceq, wred, t);
  int grun = gbase, erun = ebase;
  unsigned selmask = 0;
  int csel = 0;
  for (int i = 0; i < 16; ++i) {
    const int n = n0 + i;
    const uint32_t key = f2key(sraw[n]);
    const bool gt = key > T, eq = key == T;
    const bool mem = gt || (eq && erun < tieTake);
    int sel;
    if (mem) {
      sel = 1;
    } else {
      const int members_before = grun + (erun < tieTake ? erun : tieTake);
      const int p = n - members_before;
      sel = psel[b * N_REM + p];
    }
    selmask |= (unsigned)sel << i;
    csel += sel;
    grun += gt;
    erun += eq;
  }
  int q = scan1024(csel, wred, t);
  for (int i = 0; i < 16; ++i) {
    if ((selmask >> i) & 1) {
      const int n = n0 + i;
      sel_ws[b * K_SEL + q] = n;
      out_selidx[b * K_SEL + q] = (float)n;
      ++q;
    }
  }
}

// ---- K4: gather selected feature rows (2 rows per 256-thr block) ---------
__global__ __launch_bounds__(256) void gather_kernel(
    const float* __restrict__ feat, const int* __restrict__ sel_ws,
    float* __restrict__ out_sel) {
  const int qa = blockIdx.x * 2 + (threadIdx.x >> 7);
  const int tl = threadIdx.x & 127;
  const int b = qa / K_SEL;
  const int n = sel_ws[qa];
  const float4* src =
      reinterpret_cast<const float4*>(feat + (size_t)(b * N + n) * D);
  float4* dst = reinterpret_cast<float4*>(out_sel + (size_t)qa * D);
  dst[tl] = src[tl];
}

extern "C" void kernel_launch(void* const* d_in, const int* in_sizes, int n_in,
                              void* d_out, int out_size, void* d_ws,
                              size_t ws_size, hipStream_t stream) {
  const float* feat = (const float*)d_in[0];
  const float* WV = (const float*)d_in[1];
  const float* bV = (const float*)d_in[2];
  const float* WU = (const float*)d_in[3];
  const float* bU = (const float*)d_in[4];
  const float* watt = (const float*)d_in[5];
  const float* batt = (const float*)d_in[6];
  (void)batt;  // softmax is shift-invariant; b_att cancels in all outputs

  float* out = (float*)d_out;
  float* out_selected = out;                      // B*K_SEL*D floats
  float* out_attn = out + (size_t)B * K_SEL * D;  // B*N floats
  float* out_selidx = out_attn + (size_t)B * N;   // B*K_SEL floats

  _Float16* wt_h = (_Float16*)d_ws;              // 512 KB
  _Float16* wt_l = wt_h + 512 * 512;             // 512 KB
  float* rawp = (float*)(wt_l + 512 * 512);      // 2*NROWS floats
  uint32_t* ghist16 = (uint32_t*)(rawp + 2 * NROWS);  // 4*65536 = 1 MB
  float* gpart = (float*)(ghist16 + 4 * 65536);  // 128 floats
  int* psel = (int*)(gpart + 128);               // B*N_REM
  int* sel_ws = psel + B * N_REM;                // B*K_SEL

  prep_kernel<<<132, 256, 0, stream>>>(WV, WU, wt_h, wt_l, psel, ghist16);
  score_kernel<<<(NROWS / 128) * 2, 512, 0, stream>>>(feat, wt_h, wt_l, bV, bU,
                                                      watt, rawp);
  sumhist_kernel<<<128, 512, 0, stream>>>(rawp, ghist16, gpart);
  select_kernel<<<B, 1024, 0, stream>>>(rawp, psel, ghist16, gpart, out_attn,
                                        sel_ws, out_selidx);
  gather_kernel<<<(B * K_SEL) / 2, 256, 0, stream>>>(feat, sel_ws,
                                                     out_selected);
}